// Round 22
// baseline (107.053 us; speedup 1.0000x reference)
//
#include <hip/hip_runtime.h>
#include <hip/hip_bf16.h>

#define BB 64
#define SS 333
#define NH 8
#define DH 64
#define NI 512
#define DM 333
#define M1 21312      // BB*SS
#define KP 384        // padded K for vocab GEMM (333 -> 384)
#define NQ 1536       // fused col count [Q|K|V]
#define RS1 1536      // Y row stride (shorts)
#define VT2 110889    // 333*333 (per-head QEt slice)
#define QKSC 0.180336879f   // 0.125 * log2(e)
#define SHFT 23.0831227f    // 16 * log2(e)

typedef __attribute__((ext_vector_type(8))) short short8v;
typedef __attribute__((ext_vector_type(4))) float f32x4;

__device__ inline short f2bf(float f) {
    unsigned u = __float_as_uint(f);
    u += 0x7fffu + ((u >> 16) & 1u);
    return (short)(u >> 16);
}

__device__ __forceinline__ void gload16(const void* g, void* l) {
    __builtin_amdgcn_global_load_lds(
        (const __attribute__((address_space(1))) void*)g,
        (__attribute__((address_space(3))) void*)l, 16, 0, 0);
}

// ---------------- K0: all f32->bf16 conversions in ONE launch ----------------
#define CN0 (SS * DH)        // 21312
#define CN1 (DM * KP)        // 127872
#define CN2 (NQ * KP)        // 589824
#define CN3 (384 * NI)       // 196608
#define CNT (CN0 + CN1 + CN2 + CN3)

__global__ __launch_bounds__(256) void conv_all_kernel(
    const float* __restrict__ Er, const float* __restrict__ emb,
    const float* __restrict__ Wq, const float* __restrict__ Wk,
    const float* __restrict__ Wv, const float* __restrict__ Wo,
    short* __restrict__ eb, short* __restrict__ embb,
    short* __restrict__ wt, short* __restrict__ wot)
{
    int i = blockIdx.x * 256 + threadIdx.x;
    if (i < CN0) {
        eb[i] = f2bf(Er[i]);
        return;
    }
    i -= CN0;
    if (i < CN1) {
        int v = i / KP, k = i - v * KP;
        embb[i] = (k < DM) ? f2bf(emb[(size_t)v * DM + k]) : (short)0;
        return;
    }
    i -= CN1;
    if (i < CN2) {
        int n = i / KP, k = i - n * KP;
        int mat = n >> 9, c = n & 511;
        const float* W = (mat == 0) ? Wq : (mat == 1) ? Wk : Wv;
        wt[i] = (k < DM) ? f2bf(W[(size_t)k * NI + c]) : (short)0;
        return;
    }
    i -= CN2;
    if (i < CN3) {
        int n = i >> 9, k = i & 511;
        wot[i] = (n < DM) ? f2bf(Wo[(size_t)k * DM + n]) : (short)0;
    }
}

// ---------------- K1: vocab GEMM  Y[v,n] = embb[v,:] @ wt[n,:] + bias[n] --------------
__global__ __launch_bounds__(256) void yqkv_kernel(
    const short* __restrict__ embb, const short* __restrict__ wt,
    const float* __restrict__ bq, const float* __restrict__ bk, const float* __restrict__ bv,
    short* __restrict__ Y)
{
    __shared__ __align__(16) short abuf[2][128 * 64];
    __shared__ __align__(16) short bbuf[2][128 * 64];

    const int row0 = blockIdx.x * 128;
    const int n0   = blockIdx.y * 128;
    const int t = threadIdx.x;
    const int lane = t & 63, w = t >> 6;
    const int l15 = lane & 15, lq = lane >> 4;
    const int wr = w >> 1, wc = w & 1;

    f32x4 acc[4][4];
#pragma unroll
    for (int mi = 0; mi < 4; ++mi)
#pragma unroll
        for (int nj = 0; nj < 4; ++nj) { f32x4 z = {0.f,0.f,0.f,0.f}; acc[mi][nj] = z; }

    auto stage = [&](int buf, int k0) {
#pragma unroll
        for (int i = 0; i < 4; ++i) {
            int idx = (w * 4 + i) * 64 + lane;
            int row = idx >> 3, sp = idx & 7;
            int ar = row0 + row; ar = ar < DM ? ar : DM - 1;
            gload16(embb + (size_t)ar * KP + k0 + ((sp ^ (row & 7)) << 3),
                    &abuf[buf][(w * 4 + i) * 512]);
        }
#pragma unroll
        for (int i = 0; i < 4; ++i) {
            int idx = (w * 4 + i) * 64 + lane;
            int row = idx >> 3, sp = idx & 7;
            gload16(wt + (size_t)(n0 + row) * KP + k0 + ((sp ^ (row & 7)) << 3),
                    &bbuf[buf][(w * 4 + i) * 512]);
        }
    };

    stage(0, 0);
    __syncthreads();
    for (int tk = 0; tk < 6; ++tk) {
        if (tk < 5) stage((tk + 1) & 1, (tk + 1) * 64);
        const short* ab = abuf[tk & 1];
        const short* bb = bbuf[tk & 1];
#pragma unroll
        for (int kh = 0; kh < 2; ++kh) {
            short8v af[4], bfv[4];
#pragma unroll
            for (int mi = 0; mi < 4; ++mi) {
                int row = wr * 64 + mi * 16 + l15;
                int sp = (lq + 4 * kh) ^ (row & 7);
                af[mi] = *(const short8v*)(ab + row * 64 + sp * 8);
            }
#pragma unroll
            for (int nj = 0; nj < 4; ++nj) {
                int row = wc * 64 + nj * 16 + l15;
                int sp = (lq + 4 * kh) ^ (row & 7);
                bfv[nj] = *(const short8v*)(bb + row * 64 + sp * 8);
            }
            __builtin_amdgcn_s_setprio(1);
#pragma unroll
            for (int mi = 0; mi < 4; ++mi)
#pragma unroll
                for (int nj = 0; nj < 4; ++nj)
                    acc[mi][nj] = __builtin_amdgcn_mfma_f32_16x16x32_bf16(af[mi], bfv[nj], acc[mi][nj], 0, 0, 0);
            __builtin_amdgcn_s_setprio(0);
        }
        __syncthreads();
    }

    const int mat = n0 >> 9;
    const float* bias = (mat == 0) ? bq : (mat == 1) ? bk : bv;
    const int cb = (n0 & 511) + wc * 64;
#pragma unroll
    for (int nj = 0; nj < 4; ++nj) {
        float bvv = bias[cb + nj * 16 + l15];
        int colg = n0 + wc * 64 + nj * 16 + l15;
#pragma unroll
        for (int mi = 0; mi < 4; ++mi)
#pragma unroll
            for (int r = 0; r < 4; ++r) {
                int rowg = row0 + wr * 64 + mi * 16 + lq * 4 + r;
                Y[(size_t)rowg * NQ + colg] = f2bf(acc[mi][nj][r] + bvv);
            }
    }
}

// ---------------- K1b: QE table  QEt[h][v][l] = (0.125*q(v).Er[l] - 16)*log2e ---------
// exp folded to exp2: P = exp2(qk*QKSC + QEt). 333x333 f32 per head.
__global__ __launch_bounds__(256) void qet_kernel(
    const short* __restrict__ Y, const short* __restrict__ eb,
    float* __restrict__ QEt)
{
    __shared__ __align__(16) short abuf[128 * 64];
    __shared__ __align__(16) short bbuf[128 * 64];

    const int row0 = blockIdx.x * 128;   // vi tile
    const int n0   = blockIdx.y * 128;   // l tile
    const int h    = blockIdx.z;
    const int t = threadIdx.x;
    const int lane = t & 63, w = t >> 6;
    const int l15 = lane & 15, lq = lane >> 4;
    const int wr = w >> 1, wc = w & 1;

#pragma unroll
    for (int i = 0; i < 4; ++i) {
        int idx = (w * 4 + i) * 64 + lane;
        int row = idx >> 3, sp = idx & 7;
        int ar = row0 + row; ar = ar < DM ? ar : DM - 1;
        gload16(Y + (size_t)ar * RS1 + h * 64 + ((sp ^ (row & 7)) << 3),
                &abuf[(w * 4 + i) * 512]);
    }
#pragma unroll
    for (int i = 0; i < 4; ++i) {
        int idx = (w * 4 + i) * 64 + lane;
        int row = idx >> 3, sp = idx & 7;
        int br = n0 + row; br = br < SS ? br : SS - 1;
        gload16(eb + (size_t)br * DH + ((sp ^ (row & 7)) << 3),
                &bbuf[(w * 4 + i) * 512]);
    }
    __syncthreads();

    f32x4 acc[4][4];
#pragma unroll
    for (int mi = 0; mi < 4; ++mi)
#pragma unroll
        for (int nj = 0; nj < 4; ++nj) { f32x4 z = {0.f,0.f,0.f,0.f}; acc[mi][nj] = z; }

#pragma unroll
    for (int kh = 0; kh < 2; ++kh) {
        short8v af[4], bfv[4];
#pragma unroll
        for (int mi = 0; mi < 4; ++mi) {
            int row = wr * 64 + mi * 16 + l15;
            int sp = (lq + 4 * kh) ^ (row & 7);
            af[mi] = *(const short8v*)(abuf + row * 64 + sp * 8);
        }
#pragma unroll
        for (int nj = 0; nj < 4; ++nj) {
            int row = wc * 64 + nj * 16 + l15;
            int sp = (lq + 4 * kh) ^ (row & 7);
            bfv[nj] = *(const short8v*)(bbuf + row * 64 + sp * 8);
        }
#pragma unroll
        for (int mi = 0; mi < 4; ++mi)
#pragma unroll
            for (int nj = 0; nj < 4; ++nj)
                acc[mi][nj] = __builtin_amdgcn_mfma_f32_16x16x32_bf16(af[mi], bfv[nj], acc[mi][nj], 0, 0, 0);
    }

    float* Qh = QEt + (size_t)h * VT2;
#pragma unroll
    for (int nj = 0; nj < 4; ++nj) {
        int colg = n0 + wc * 64 + nj * 16 + l15;
#pragma unroll
        for (int mi = 0; mi < 4; ++mi)
#pragma unroll
            for (int r = 0; r < 4; ++r) {
                int rowg = row0 + wr * 64 + mi * 16 + lq * 4 + r;
                if (rowg < SS && colg < SS)
                    Qh[(size_t)rowg * SS + colg] = acc[mi][nj][r] * QKSC - SHFT;
            }
    }
}

// ---------------- K2: batch-paired flash MFMA attention, QE-table gather -------------
// Block = (h, ti, batch-pair): group 0 (waves 0-3) = batch 2bp, group 1 = batch 2bp+1,
// BOTH on q-tile ti -> zero idle wave-groups. P = exp2(qk*QKSC + QEt[tok_i][SS-1-i+j])
// (exp and fixed-max folded into the table); masked -> 0; deferred row-sum at epilogue.
// li clamps removed: out-of-range li occurs only for masked/padded rows whose values
// are discarded (store guard i<SS; MFMA rows independent); overrun <=248B stays inside
// the workspace. waves_per_eu(4,4): VGPR 64, no spill. LDS 66.7 KB.
__global__ __launch_bounds__(512) __attribute__((amdgpu_waves_per_eu(4, 4)))
void attn_mfma_kernel(
    const short* __restrict__ Y, const int* __restrict__ xs,
    const float* __restrict__ QEt, short* __restrict__ attnb)
{
    __shared__ __align__(16) short k_lds[2][64 * 64];  // per-group [key][d], seg-swz key&7
    __shared__ __align__(16) short vT_lds[2][64 * 64]; // per-group [d][key], seg-swz d&7
    __shared__ __align__(16) short vrow[2][64 * 64];   // per-group V row-staging (linear)
    __shared__ __align__(16) short p_lds[128 * 64];    // 8 waves x 2KB P tiles
    __shared__ int tok_lds[2][SS];

    const int p = blockIdx.x;
    const int h = p & 7;                 // XCD pin (p%8)
    const int rem = p >> 3;
    const int tid = rem >> 5;            // 0..5, dispatch-ordered
    const int bp  = rem & 31;            // batch pair
    const int ti  = 5 - tid;             // long blocks first
    const int t = threadIdx.x;           // 0..511
    const int lane = t & 63, w = t >> 6; // w 0..7
    const int l15 = lane & 15, lq = lane >> 4;
    const int g  = w >> 2;               // group (batch select)
    const int wl = w & 3;                // wave-in-group = strip index
    const int b  = bp * 2 + g;
    const int iw = ti * 64 + 16 * wl;
    const int tl = t & 255;              // thread within group

    for (int idx = t; idx < SS; idx += 512) tok_lds[0][idx] = xs[(bp * 2) * SS + idx];
    for (int idx = t; idx < SS; idx += 512) tok_lds[1][idx] = xs[(bp * 2 + 1) * SS + idx];
    __syncthreads();

    const short* Yh = Y + h * 64;
    const float* QEh = QEt + (size_t)h * VT2;
    const int* tok = tok_lds[g];

    // ---- Q fragments + per-row QEt gather bases (hoisted out of the js loop) ----
    int qr = iw + l15; if (qr > SS - 1) qr = SS - 1;
    const short* qrow = Yh + (size_t)tok[qr] * RS1;
    const short8v qa0 = *(const short8v*)(qrow + lq * 8);
    const short8v qa1 = *(const short8v*)(qrow + 32 + lq * 8);

    int libase[4];
#pragma unroll
    for (int r = 0; r < 4; ++r) {
        int i_ = iw + lq * 4 + r;
        int ic = i_ > SS - 1 ? SS - 1 : i_;
        libase[r] = tok[ic] * SS + (SS - 1) - i_;    // + j gives the table column
    }

    float l4[4];
    f32x4 o[4];
#pragma unroll
    for (int r = 0; r < 4; ++r) { l4[r] = 0.f; }
#pragma unroll
    for (int nd = 0; nd < 4; ++nd) { f32x4 z = {0.f, 0.f, 0.f, 0.f}; o[nd] = z; }

    asm volatile("s_waitcnt vmcnt(0)" ::: "memory");

    for (int js = 0; js <= ti; ++js) {
        const int j0 = js * 64;
        __syncthreads();                 // barrier A: prev compute done, buffers free
        // ---- V row stage (group-local: 2 gloads/thread; oldest on the counter) ----
#pragma unroll
        for (int it = 0; it < 2; ++it) {
            int task = it * 256 + tl;
            int row = task >> 3, sp = task & 7;
            int jg = j0 + row; if (jg > SS - 1) jg = SS - 1;
            gload16(Yh + (size_t)tok[jg] * RS1 + 1024 + ((sp ^ (row & 7)) << 3),
                    &vrow[g][(size_t)(it * 256 + (tl & 192)) * 8]);
        }
        // ---- K stage (group-local: 2 gloads/thread) ----
#pragma unroll
        for (int it = 0; it < 2; ++it) {
            int task = it * 256 + tl;
            int row = task >> 3, sp = task & 7;
            int jg = j0 + row; if (jg > SS - 1) jg = SS - 1;
            gload16(Yh + (size_t)tok[jg] * RS1 + 512 + ((sp ^ (row & 7)) << 3),
                    &k_lds[g][(size_t)(it * 256 + (tl & 192)) * 8]);
        }
        asm volatile("s_waitcnt vmcnt(2)" ::: "memory");
        // ---- wave-local V transpose: wave wl transposes its own octets {wl, 4+wl} ----
#pragma unroll
        for (int it = 0; it < 2; ++it) {
            const int kc = it * 4 + wl;
            const int d = lane;
            short8v vv;
#pragma unroll
            for (int j = 0; j < 8; ++j)
                vv[j] = vrow[g][(kc * 8 + j) * 64 + (((d >> 3) ^ j) << 3) + (d & 7)];
            *(short8v*)(vT_lds[g] + (size_t)d * 64 + ((kc ^ (d & 7)) << 3)) = vv;
        }
        __syncthreads();                 // barrier B: k_lds + vT ready

        // ---- every wave active: QK, QEt gather, P write, PV ----
        {
            const short* kb = k_lds[g];
            f32x4 sc[4];
            __builtin_amdgcn_s_setprio(1);
#pragma unroll
            for (int n = 0; n < 4; ++n) {
                int row = n * 16 + l15;
                short8v k0 = *(const short8v*)((char*)kb + ((row * 128 + lq * 16) ^ ((row & 7) << 4)));
                short8v k1 = *(const short8v*)((char*)kb + ((row * 128 + 64 + lq * 16) ^ ((row & 7) << 4)));
                f32x4 z = {0.f, 0.f, 0.f, 0.f};
                z = __builtin_amdgcn_mfma_f32_16x16x32_bf16(qa0, k0, z, 0, 0, 0);
                sc[n] = __builtin_amdgcn_mfma_f32_16x16x32_bf16(qa1, k1, z, 0, 0, 0);
            }
            __builtin_amdgcn_s_setprio(0);

            short* pw = p_lds + w * 1024;
#pragma unroll
            for (int n = 0; n < 4; ++n) {
                int jrel = n * 16 + l15;
                int jg = j0 + jrel;
#pragma unroll
                for (int r = 0; r < 4; ++r) {
                    int irel = lq * 4 + r;
                    float qet = QEh[libase[r] + jg];
                    bool ok = jg <= (iw + irel);
                    float pv = ok ? __builtin_amdgcn_exp2f(sc[n][r] * QKSC + qet) : 0.f;
                    l4[r] += pv;
                    *(short*)((char*)pw + ((irel * 128 + jrel * 2) ^ ((irel & 7) << 4))) = f2bf(pv);
                }
            }

            __builtin_amdgcn_s_setprio(1);
#pragma unroll
            for (int kb2 = 0; kb2 < 2; ++kb2) {
                short8v pa = *(const short8v*)((char*)pw + ((l15 * 128 + kb2 * 64 + lq * 16) ^ ((l15 & 7) << 4)));
#pragma unroll
                for (int nd = 0; nd < 4; ++nd) {
                    int d = nd * 16 + l15;
                    short8v vf = *(const short8v*)((char*)vT_lds[g] + ((size_t)d * 128 + (((kb2 * 4 + lq) ^ (d & 7)) << 4)));
                    o[nd] = __builtin_amdgcn_mfma_f32_16x16x32_bf16(pa, vf, o[nd], 0, 0, 0);
                }
            }
            __builtin_amdgcn_s_setprio(0);
        }
    }

    // ---- epilogue: finish l-reduction, normalize, store bf16 (B,S,INNER) ----
#pragma unroll
    for (int r = 0; r < 4; ++r) {
        float ls = l4[r];
        ls += __shfl_xor(ls, 1);
        ls += __shfl_xor(ls, 2);
        ls += __shfl_xor(ls, 4);
        ls += __shfl_xor(ls, 8);
        int i = iw + lq * 4 + r;
        if (i < SS) {
            float rl = 1.0f / ls;
#pragma unroll
            for (int nd = 0; nd < 4; ++nd)
                attnb[(size_t)(b * SS + i) * NI + h * 64 + nd * 16 + l15] = f2bf(o[nd][r] * rl);
        }
    }
}

// ---------------- K3: out = attnb[M1,512] @ wot^T + bo, f32 out ----------------
__global__ __launch_bounds__(256) void oproj_mfma_kernel(
    const short* __restrict__ ab_g, const short* __restrict__ wot,
    const float* __restrict__ bo, float* __restrict__ out)
{
    __shared__ __align__(16) short abuf[2][128 * 64];
    __shared__ __align__(16) short bbuf[2][128 * 64];

    const int row0 = blockIdx.x * 128;
    const int n0   = blockIdx.y * 128;
    const int t = threadIdx.x;
    const int lane = t & 63, w = t >> 6;
    const int l15 = lane & 15, lq = lane >> 4;
    const int wr = w >> 1, wc = w & 1;

    f32x4 acc[4][4];
#pragma unroll
    for (int mi = 0; mi < 4; ++mi)
#pragma unroll
        for (int nj = 0; nj < 4; ++nj) { f32x4 z = {0.f,0.f,0.f,0.f}; acc[mi][nj] = z; }

    auto stage = [&](int buf, int k0) {
#pragma unroll
        for (int i = 0; i < 4; ++i) {
            int idx = (w * 4 + i) * 64 + lane;
            int row = idx >> 3, sp = idx & 7;
            int rg = row0 + row; rg = rg < M1 ? rg : M1 - 1;
            gload16(ab_g + (size_t)rg * NI + k0 + ((sp ^ (row & 7)) << 3),
                    &abuf[buf][(w * 4 + i) * 512]);
        }
#pragma unroll
        for (int i = 0; i < 4; ++i) {
            int idx = (w * 4 + i) * 64 + lane;
            int row = idx >> 3, sp = idx & 7;
            gload16(wot + (size_t)(n0 + row) * NI + k0 + ((sp ^ (row & 7)) << 3),
                    &bbuf[buf][(w * 4 + i) * 512]);
        }
    };

    stage(0, 0);
    __syncthreads();
    for (int tk = 0; tk < 8; ++tk) {
        if (tk < 7) stage((tk + 1) & 1, (tk + 1) * 64);
        const short* ab = abuf[tk & 1];
        const short* bb = bbuf[tk & 1];
#pragma unroll
        for (int kh = 0; kh < 2; ++kh) {
            short8v af[4], bfv[4];
#pragma unroll
            for (int mi = 0; mi < 4; ++mi) {
                int row = wr * 64 + mi * 16 + l15;
                int sp = (lq + 4 * kh) ^ (row & 7);
                af[mi] = *(const short8v*)(ab + row * 64 + sp * 8);
            }
#pragma unroll
            for (int nj = 0; nj < 4; ++nj) {
                int row = wc * 64 + nj * 16 + l15;
                int sp = (lq + 4 * kh) ^ (row & 7);
                bfv[nj] = *(const short8v*)(bb + row * 64 + sp * 8);
            }
            __builtin_amdgcn_s_setprio(1);
#pragma unroll
            for (int mi = 0; mi < 4; ++mi)
#pragma unroll
                for (int nj = 0; nj < 4; ++nj)
                    acc[mi][nj] = __builtin_amdgcn_mfma_f32_16x16x32_bf16(af[mi], bfv[nj], acc[mi][nj], 0, 0, 0);
            __builtin_amdgcn_s_setprio(0);
        }
        __syncthreads();
    }

#pragma unroll
    for (int nj = 0; nj < 4; ++nj) {
        int colg = n0 + wc * 64 + nj * 16 + l15;
        float bvv = (colg < DM) ? bo[colg] : 0.f;
#pragma unroll
        for (int mi = 0; mi < 4; ++mi)
#pragma unroll
            for (int r = 0; r < 4; ++r) {
                int rowg = row0 + wr * 64 + mi * 16 + lq * 4 + r;
                if (rowg < M1 && colg < DM)
                    out[(size_t)rowg * DM + colg] = acc[mi][nj][r] + bvv;
            }
    }
}

extern "C" void kernel_launch(void* const* d_in, const int* in_sizes, int n_in,
                              void* d_out, int out_size, void* d_ws, size_t ws_size,
                              hipStream_t stream) {
    const int*   xs  = (const int*)d_in[0];
    const float* emb = (const float*)d_in[1];
    const float* Wq  = (const float*)d_in[2];
    const float* bq  = (const float*)d_in[3];
    const float* Wk  = (const float*)d_in[4];
    const float* bk  = (const float*)d_in[5];
    const float* Wv  = (const float*)d_in[6];
    const float* bv  = (const float*)d_in[7];
    const float* Er  = (const float*)d_in[8];
    const float* Wo  = (const float*)d_in[9];
    const float* bo  = (const float*)d_in[10];
    float* out = (float*)d_out;

    short* attnb = (short*)d_ws;                       // M1*512
    short* Y    = attnb + (size_t)M1 * NI;             // 384*1536 (token QKV table)
    short* embb = Y + (size_t)384 * NQ;                // DM*KP
    short* wt   = embb + (size_t)DM * KP;              // NQ*KP
    short* wot  = wt + (size_t)NQ * KP;                // 384*NI
    short* eb   = wot + (size_t)384 * NI;              // SS*DH
    float* QEt  = (float*)(eb + (size_t)SS * DH);      // 8*333*333 f32 + guard slack

    conv_all_kernel<<<(CNT + 255) / 256, 256, 0, stream>>>(Er, emb, Wq, Wk, Wv, Wo,
                                                           eb, embb, wt, wot);
    dim3 g1(3, 12);
    yqkv_kernel<<<g1, 256, 0, stream>>>(embb, wt, bq, bk, bv, Y);
    dim3 g2(3, 3, 8);
    qet_kernel<<<g2, 256, 0, stream>>>(Y, eb, QEt);
    attn_mfma_kernel<<<BB * NH * 3, 512, 0, stream>>>(Y, xs, QEt, attnb);
    dim3 g3((M1 + 127) / 128, 3);
    oproj_mfma_kernel<<<g3, 256, 0, stream>>>(attnb, wot, bo, out);
}

// Round 23
// 104.754 us; speedup vs baseline: 1.0219x; 1.0219x over previous
//
#include <hip/hip_runtime.h>
#include <hip/hip_bf16.h>

#define BB 64
#define SS 333
#define NH 8
#define DH 64
#define NI 512
#define DM 333
#define M1 21312      // BB*SS
#define KP 384        // padded K for vocab GEMM (333 -> 384)
#define NQ 1536       // fused col count [Q|K|V]
#define RS1 1536      // Y row stride (shorts)
#define VT2 110889    // 333*333 (per-head QEt slice)

typedef __attribute__((ext_vector_type(8))) short short8v;
typedef __attribute__((ext_vector_type(4))) float f32x4;

__device__ inline short f2bf(float f) {
    unsigned u = __float_as_uint(f);
    u += 0x7fffu + ((u >> 16) & 1u);
    return (short)(u >> 16);
}

__device__ __forceinline__ void gload16(const void* g, void* l) {
    __builtin_amdgcn_global_load_lds(
        (const __attribute__((address_space(1))) void*)g,
        (__attribute__((address_space(3))) void*)l, 16, 0, 0);
}

// ---------------- K0: all f32->bf16 conversions in ONE launch ----------------
#define CN0 (SS * DH)        // 21312
#define CN1 (DM * KP)        // 127872
#define CN2 (NQ * KP)        // 589824
#define CN3 (384 * NI)       // 196608
#define CNT (CN0 + CN1 + CN2 + CN3)

__global__ __launch_bounds__(256) void conv_all_kernel(
    const float* __restrict__ Er, const float* __restrict__ emb,
    const float* __restrict__ Wq, const float* __restrict__ Wk,
    const float* __restrict__ Wv, const float* __restrict__ Wo,
    short* __restrict__ eb, short* __restrict__ embb,
    short* __restrict__ wt, short* __restrict__ wot)
{
    int i = blockIdx.x * 256 + threadIdx.x;
    if (i < CN0) {
        eb[i] = f2bf(Er[i]);
        return;
    }
    i -= CN0;
    if (i < CN1) {
        int v = i / KP, k = i - v * KP;
        embb[i] = (k < DM) ? f2bf(emb[(size_t)v * DM + k]) : (short)0;
        return;
    }
    i -= CN1;
    if (i < CN2) {
        int n = i / KP, k = i - n * KP;
        int mat = n >> 9, c = n & 511;
        const float* W = (mat == 0) ? Wq : (mat == 1) ? Wk : Wv;
        wt[i] = (k < DM) ? f2bf(W[(size_t)k * NI + c]) : (short)0;
        return;
    }
    i -= CN2;
    if (i < CN3) {
        int n = i >> 9, k = i & 511;
        wot[i] = (n < DM) ? f2bf(Wo[(size_t)k * DM + n]) : (short)0;
    }
}

// ---------------- K1: vocab GEMM  Y[v,n] = embb[v,:] @ wt[n,:] + bias[n] --------------
__global__ __launch_bounds__(256) void yqkv_kernel(
    const short* __restrict__ embb, const short* __restrict__ wt,
    const float* __restrict__ bq, const float* __restrict__ bk, const float* __restrict__ bv,
    short* __restrict__ Y)
{
    __shared__ __align__(16) short abuf[2][128 * 64];
    __shared__ __align__(16) short bbuf[2][128 * 64];

    const int row0 = blockIdx.x * 128;
    const int n0   = blockIdx.y * 128;
    const int t = threadIdx.x;
    const int lane = t & 63, w = t >> 6;
    const int l15 = lane & 15, lq = lane >> 4;
    const int wr = w >> 1, wc = w & 1;

    f32x4 acc[4][4];
#pragma unroll
    for (int mi = 0; mi < 4; ++mi)
#pragma unroll
        for (int nj = 0; nj < 4; ++nj) { f32x4 z = {0.f,0.f,0.f,0.f}; acc[mi][nj] = z; }

    auto stage = [&](int buf, int k0) {
#pragma unroll
        for (int i = 0; i < 4; ++i) {
            int idx = (w * 4 + i) * 64 + lane;
            int row = idx >> 3, sp = idx & 7;
            int ar = row0 + row; ar = ar < DM ? ar : DM - 1;
            gload16(embb + (size_t)ar * KP + k0 + ((sp ^ (row & 7)) << 3),
                    &abuf[buf][(w * 4 + i) * 512]);
        }
#pragma unroll
        for (int i = 0; i < 4; ++i) {
            int idx = (w * 4 + i) * 64 + lane;
            int row = idx >> 3, sp = idx & 7;
            gload16(wt + (size_t)(n0 + row) * KP + k0 + ((sp ^ (row & 7)) << 3),
                    &bbuf[buf][(w * 4 + i) * 512]);
        }
    };

    stage(0, 0);
    __syncthreads();
    for (int tk = 0; tk < 6; ++tk) {
        if (tk < 5) stage((tk + 1) & 1, (tk + 1) * 64);
        const short* ab = abuf[tk & 1];
        const short* bb = bbuf[tk & 1];
#pragma unroll
        for (int kh = 0; kh < 2; ++kh) {
            short8v af[4], bfv[4];
#pragma unroll
            for (int mi = 0; mi < 4; ++mi) {
                int row = wr * 64 + mi * 16 + l15;
                int sp = (lq + 4 * kh) ^ (row & 7);
                af[mi] = *(const short8v*)(ab + row * 64 + sp * 8);
            }
#pragma unroll
            for (int nj = 0; nj < 4; ++nj) {
                int row = wc * 64 + nj * 16 + l15;
                int sp = (lq + 4 * kh) ^ (row & 7);
                bfv[nj] = *(const short8v*)(bb + row * 64 + sp * 8);
            }
            __builtin_amdgcn_s_setprio(1);
#pragma unroll
            for (int mi = 0; mi < 4; ++mi)
#pragma unroll
                for (int nj = 0; nj < 4; ++nj)
                    acc[mi][nj] = __builtin_amdgcn_mfma_f32_16x16x32_bf16(af[mi], bfv[nj], acc[mi][nj], 0, 0, 0);
            __builtin_amdgcn_s_setprio(0);
        }
        __syncthreads();
    }

    const int mat = n0 >> 9;
    const float* bias = (mat == 0) ? bq : (mat == 1) ? bk : bv;
    const int cb = (n0 & 511) + wc * 64;
#pragma unroll
    for (int nj = 0; nj < 4; ++nj) {
        float bvv = bias[cb + nj * 16 + l15];
        int colg = n0 + wc * 64 + nj * 16 + l15;
#pragma unroll
        for (int mi = 0; mi < 4; ++mi)
#pragma unroll
            for (int r = 0; r < 4; ++r) {
                int rowg = row0 + wr * 64 + mi * 16 + lq * 4 + r;
                Y[(size_t)rowg * NQ + colg] = f2bf(acc[mi][nj][r] + bvv);
            }
    }
}

// ---------------- K1b: QE table  QEt[h][v][l] = 0.125 * q(v).Er[l] - 16 ---------------
__global__ __launch_bounds__(256) void qet_kernel(
    const short* __restrict__ Y, const short* __restrict__ eb,
    float* __restrict__ QEt)
{
    __shared__ __align__(16) short abuf[128 * 64];
    __shared__ __align__(16) short bbuf[128 * 64];

    const int row0 = blockIdx.x * 128;   // vi tile
    const int n0   = blockIdx.y * 128;   // l tile
    const int h    = blockIdx.z;
    const int t = threadIdx.x;
    const int lane = t & 63, w = t >> 6;
    const int l15 = lane & 15, lq = lane >> 4;
    const int wr = w >> 1, wc = w & 1;

#pragma unroll
    for (int i = 0; i < 4; ++i) {
        int idx = (w * 4 + i) * 64 + lane;
        int row = idx >> 3, sp = idx & 7;
        int ar = row0 + row; ar = ar < DM ? ar : DM - 1;
        gload16(Y + (size_t)ar * RS1 + h * 64 + ((sp ^ (row & 7)) << 3),
                &abuf[(w * 4 + i) * 512]);
    }
#pragma unroll
    for (int i = 0; i < 4; ++i) {
        int idx = (w * 4 + i) * 64 + lane;
        int row = idx >> 3, sp = idx & 7;
        int br = n0 + row; br = br < SS ? br : SS - 1;
        gload16(eb + (size_t)br * DH + ((sp ^ (row & 7)) << 3),
                &bbuf[(w * 4 + i) * 512]);
    }
    __syncthreads();

    f32x4 acc[4][4];
#pragma unroll
    for (int mi = 0; mi < 4; ++mi)
#pragma unroll
        for (int nj = 0; nj < 4; ++nj) { f32x4 z = {0.f,0.f,0.f,0.f}; acc[mi][nj] = z; }

#pragma unroll
    for (int kh = 0; kh < 2; ++kh) {
        short8v af[4], bfv[4];
#pragma unroll
        for (int mi = 0; mi < 4; ++mi) {
            int row = wr * 64 + mi * 16 + l15;
            int sp = (lq + 4 * kh) ^ (row & 7);
            af[mi] = *(const short8v*)(abuf + row * 64 + sp * 8);
        }
#pragma unroll
        for (int nj = 0; nj < 4; ++nj) {
            int row = wc * 64 + nj * 16 + l15;
            int sp = (lq + 4 * kh) ^ (row & 7);
            bfv[nj] = *(const short8v*)(bbuf + row * 64 + sp * 8);
        }
#pragma unroll
        for (int mi = 0; mi < 4; ++mi)
#pragma unroll
            for (int nj = 0; nj < 4; ++nj)
                acc[mi][nj] = __builtin_amdgcn_mfma_f32_16x16x32_bf16(af[mi], bfv[nj], acc[mi][nj], 0, 0, 0);
    }

    float* Qh = QEt + (size_t)h * VT2;
#pragma unroll
    for (int nj = 0; nj < 4; ++nj) {
        int colg = n0 + wc * 64 + nj * 16 + l15;
#pragma unroll
        for (int mi = 0; mi < 4; ++mi)
#pragma unroll
            for (int r = 0; r < 4; ++r) {
                int rowg = row0 + wr * 64 + mi * 16 + lq * 4 + r;
                if (rowg < SS && colg < SS)
                    Qh[(size_t)rowg * SS + colg] = acc[mi][nj][r] * 0.125f - 16.0f;
            }
    }
}

// ---------------- K2: batch-paired flash MFMA attention, QE-table gather -------------
// Block = (h, ti, batch-pair): group 0 (waves 0-3) = batch 2bp, group 1 = batch 2bp+1,
// BOTH on q-tile ti -> both groups need exactly ti+1 panels => zero idle wave-groups.
// Dispatch order ti descending. scores = qk*0.125 + QEt[tok_i][SS-1-i+j] (fixed-max
// folded); P = exp(score); masked -> 0; deferred row-sum at epilogue.
// waves_per_eu(4,4): per-wave state = champion's (VGPR 64, no spill). LDS 66.7 KB.
__global__ __launch_bounds__(512) __attribute__((amdgpu_waves_per_eu(4, 4)))
void attn_mfma_kernel(
    const short* __restrict__ Y, const int* __restrict__ xs,
    const float* __restrict__ QEt, short* __restrict__ attnb)
{
    __shared__ __align__(16) short k_lds[2][64 * 64];  // per-group [key][d], seg-swz key&7
    __shared__ __align__(16) short vT_lds[2][64 * 64]; // per-group [d][key], seg-swz d&7
    __shared__ __align__(16) short vrow[2][64 * 64];   // per-group V row-staging (linear)
    __shared__ __align__(16) short p_lds[128 * 64];    // 8 waves x 2KB P tiles
    __shared__ int tok_lds[2][SS];

    const int p = blockIdx.x;
    const int h = p & 7;                 // XCD pin (p%8)
    const int rem = p >> 3;
    const int tid = rem >> 5;            // 0..5, dispatch-ordered
    const int bp  = rem & 31;            // batch pair
    const int ti  = 5 - tid;             // long blocks first
    const int t = threadIdx.x;           // 0..511
    const int lane = t & 63, w = t >> 6; // w 0..7
    const int l15 = lane & 15, lq = lane >> 4;
    const int g  = w >> 2;               // group (batch select)
    const int wl = w & 3;                // wave-in-group = strip index
    const int b  = bp * 2 + g;
    const int iw = ti * 64 + 16 * wl;
    const int tl = t & 255;              // thread within group

    // stage both batches' token ids
    for (int idx = t; idx < SS; idx += 512) tok_lds[0][idx] = xs[(bp * 2) * SS + idx];
    for (int idx = t; idx < SS; idx += 512) tok_lds[1][idx] = xs[(bp * 2 + 1) * SS + idx];
    __syncthreads();

    const short* Yh = Y + h * 64;
    const float* QEh = QEt + (size_t)h * VT2;
    const int* tok = tok_lds[g];

    // ---- Q fragments + per-row QEt row offsets ----
    int qr = iw + l15; if (qr > SS - 1) qr = SS - 1;
    const short* qrow = Yh + (size_t)tok[qr] * RS1;
    const short8v qa0 = *(const short8v*)(qrow + lq * 8);
    const short8v qa1 = *(const short8v*)(qrow + 32 + lq * 8);

    int irow[4];
#pragma unroll
    for (int r = 0; r < 4; ++r) {
        int i_ = iw + lq * 4 + r; if (i_ > SS - 1) i_ = SS - 1;
        irow[r] = tok[i_] * SS;
    }

    float l4[4];
    f32x4 o[4];
#pragma unroll
    for (int r = 0; r < 4; ++r) { l4[r] = 0.f; }
#pragma unroll
    for (int nd = 0; nd < 4; ++nd) { f32x4 z = {0.f, 0.f, 0.f, 0.f}; o[nd] = z; }

    asm volatile("s_waitcnt vmcnt(0)" ::: "memory");

    for (int js = 0; js <= ti; ++js) {
        const int j0 = js * 64;
        __syncthreads();                 // barrier A: prev compute done, buffers free
        // ---- V row stage (group-local: 2 gloads/thread; oldest on the counter) ----
#pragma unroll
        for (int it = 0; it < 2; ++it) {
            int task = it * 256 + tl;
            int row = task >> 3, sp = task & 7;
            int jg = j0 + row; if (jg > SS - 1) jg = SS - 1;
            gload16(Yh + (size_t)tok[jg] * RS1 + 1024 + ((sp ^ (row & 7)) << 3),
                    &vrow[g][(size_t)(it * 256 + (tl & 192)) * 8]);
        }
        // ---- K stage (group-local: 2 gloads/thread) ----
#pragma unroll
        for (int it = 0; it < 2; ++it) {
            int task = it * 256 + tl;
            int row = task >> 3, sp = task & 7;
            int jg = j0 + row; if (jg > SS - 1) jg = SS - 1;
            gload16(Yh + (size_t)tok[jg] * RS1 + 512 + ((sp ^ (row & 7)) << 3),
                    &k_lds[g][(size_t)(it * 256 + (tl & 192)) * 8]);
        }
        // wait the 2 oldest (V) gloads; K drains at the barrier
        asm volatile("s_waitcnt vmcnt(2)" ::: "memory");
        // ---- wave-local V transpose: wave wl transposes its own octets {wl, 4+wl} ----
#pragma unroll
        for (int it = 0; it < 2; ++it) {
            const int kc = it * 4 + wl;
            const int d = lane;
            short8v vv;
#pragma unroll
            for (int j = 0; j < 8; ++j)
                vv[j] = vrow[g][(kc * 8 + j) * 64 + (((d >> 3) ^ j) << 3) + (d & 7)];
            *(short8v*)(vT_lds[g] + (size_t)d * 64 + ((kc ^ (d & 7)) << 3)) = vv;
        }
        __syncthreads();                 // barrier B: k_lds + vT ready

        // ---- every wave active: QK, QEt gather, P write, PV ----
        {
            const short* kb = k_lds[g];
            f32x4 sc[4];
            __builtin_amdgcn_s_setprio(1);
#pragma unroll
            for (int n = 0; n < 4; ++n) {
                int row = n * 16 + l15;
                short8v k0 = *(const short8v*)((char*)kb + ((row * 128 + lq * 16) ^ ((row & 7) << 4)));
                short8v k1 = *(const short8v*)((char*)kb + ((row * 128 + 64 + lq * 16) ^ ((row & 7) << 4)));
                f32x4 z = {0.f, 0.f, 0.f, 0.f};
                z = __builtin_amdgcn_mfma_f32_16x16x32_bf16(qa0, k0, z, 0, 0, 0);
                sc[n] = __builtin_amdgcn_mfma_f32_16x16x32_bf16(qa1, k1, z, 0, 0, 0);
            }
            __builtin_amdgcn_s_setprio(0);

            short* pw = p_lds + w * 1024;
#pragma unroll
            for (int n = 0; n < 4; ++n) {
                float psum[4];
#pragma unroll
                for (int r = 0; r < 4; ++r) {
                    int irel = lq * 4 + r;
                    int li = (SS - 1) - (iw + irel) + j0 + n * 16 + l15;
                    li = li < 0 ? 0 : (li > SS - 1 ? SS - 1 : li);
                    float qet = QEh[irow[r] + li];
                    int jrel = n * 16 + l15;
                    bool ok = (j0 + jrel) <= (iw + irel);
                    float pv = ok ? __expf(sc[n][r] * 0.125f + qet) : 0.f;
                    psum[r] = pv;
                    *(short*)((char*)pw + ((irel * 128 + jrel * 2) ^ ((irel & 7) << 4))) = f2bf(pv);
                }
#pragma unroll
                for (int r = 0; r < 4; ++r)
                    l4[r] += psum[r];
            }

            __builtin_amdgcn_s_setprio(1);
#pragma unroll
            for (int kb2 = 0; kb2 < 2; ++kb2) {
                short8v pa = *(const short8v*)((char*)pw + ((l15 * 128 + kb2 * 64 + lq * 16) ^ ((l15 & 7) << 4)));
#pragma unroll
                for (int nd = 0; nd < 4; ++nd) {
                    int d = nd * 16 + l15;
                    short8v vf = *(const short8v*)((char*)vT_lds[g] + ((size_t)d * 128 + (((kb2 * 4 + lq) ^ (d & 7)) << 4)));
                    o[nd] = __builtin_amdgcn_mfma_f32_16x16x32_bf16(pa, vf, o[nd], 0, 0, 0);
                }
            }
            __builtin_amdgcn_s_setprio(0);
        }
    }

    // ---- epilogue: finish l-reduction, normalize, store bf16 (B,S,INNER) ----
#pragma unroll
    for (int r = 0; r < 4; ++r) {
        float ls = l4[r];
        ls += __shfl_xor(ls, 1);
        ls += __shfl_xor(ls, 2);
        ls += __shfl_xor(ls, 4);
        ls += __shfl_xor(ls, 8);
        int i = iw + lq * 4 + r;
        if (i < SS) {
            float rl = 1.0f / ls;
#pragma unroll
            for (int nd = 0; nd < 4; ++nd)
                attnb[(size_t)(b * SS + i) * NI + h * 64 + nd * 16 + l15] = f2bf(o[nd][r] * rl);
        }
    }
}

// ---------------- K3: out = attnb[M1,512] @ wot^T + bo, f32 out ----------------
__global__ __launch_bounds__(256) void oproj_mfma_kernel(
    const short* __restrict__ ab_g, const short* __restrict__ wot,
    const float* __restrict__ bo, float* __restrict__ out)
{
    __shared__ __align__(16) short abuf[2][128 * 64];
    __shared__ __align__(16) short bbuf[2][128 * 64];

    const int row0 = blockIdx.x * 128;
    const int n0   = blockIdx.y * 128;
    const int t = threadIdx.x;
    const int lane = t & 63, w = t >> 6;
    const int l15 = lane & 15, lq = lane >> 4;
    const int wr = w >> 1, wc = w & 1;

    f32x4 acc[4][4];
#pragma unroll
    for (int mi = 0; mi < 4; ++mi)
#pragma unroll
        for (int nj = 0; nj < 4; ++nj) { f32x4 z = {0.f,0.f,0.f,0.f}; acc[mi][nj] = z; }

    auto stage = [&](int buf, int k0) {
#pragma unroll
        for (int i = 0; i < 4; ++i) {
            int idx = (w * 4 + i) * 64 + lane;
            int row = idx >> 3, sp = idx & 7;
            int rg = row0 + row; rg = rg < M1 ? rg : M1 - 1;
            gload16(ab_g + (size_t)rg * NI + k0 + ((sp ^ (row & 7)) << 3),
                    &abuf[buf][(w * 4 + i) * 512]);
        }
#pragma unroll
        for (int i = 0; i < 4; ++i) {
            int idx = (w * 4 + i) * 64 + lane;
            int row = idx >> 3, sp = idx & 7;
            gload16(wot + (size_t)(n0 + row) * NI + k0 + ((sp ^ (row & 7)) << 3),
                    &bbuf[buf][(w * 4 + i) * 512]);
        }
    };

    stage(0, 0);
    __syncthreads();
    for (int tk = 0; tk < 8; ++tk) {
        if (tk < 7) stage((tk + 1) & 1, (tk + 1) * 64);
        const short* ab = abuf[tk & 1];
        const short* bb = bbuf[tk & 1];
#pragma unroll
        for (int kh = 0; kh < 2; ++kh) {
            short8v af[4], bfv[4];
#pragma unroll
            for (int mi = 0; mi < 4; ++mi) {
                int row = wr * 64 + mi * 16 + l15;
                int sp = (lq + 4 * kh) ^ (row & 7);
                af[mi] = *(const short8v*)(ab + row * 64 + sp * 8);
            }
#pragma unroll
            for (int nj = 0; nj < 4; ++nj) {
                int row = wc * 64 + nj * 16 + l15;
                int sp = (lq + 4 * kh) ^ (row & 7);
                bfv[nj] = *(const short8v*)(bb + row * 64 + sp * 8);
            }
            __builtin_amdgcn_s_setprio(1);
#pragma unroll
            for (int mi = 0; mi < 4; ++mi)
#pragma unroll
                for (int nj = 0; nj < 4; ++nj)
                    acc[mi][nj] = __builtin_amdgcn_mfma_f32_16x16x32_bf16(af[mi], bfv[nj], acc[mi][nj], 0, 0, 0);
            __builtin_amdgcn_s_setprio(0);
        }
        __syncthreads();
    }

#pragma unroll
    for (int nj = 0; nj < 4; ++nj) {
        int colg = n0 + wc * 64 + nj * 16 + l15;
        float bvv = (colg < DM) ? bo[colg] : 0.f;
#pragma unroll
        for (int mi = 0; mi < 4; ++mi)
#pragma unroll
            for (int r = 0; r < 4; ++r) {
                int rowg = row0 + wr * 64 + mi * 16 + lq * 4 + r;
                if (rowg < M1 && colg < DM)
                    out[(size_t)rowg * DM + colg] = acc[mi][nj][r] + bvv;
            }
    }
}

extern "C" void kernel_launch(void* const* d_in, const int* in_sizes, int n_in,
                              void* d_out, int out_size, void* d_ws, size_t ws_size,
                              hipStream_t stream) {
    const int*   xs  = (const int*)d_in[0];
    const float* emb = (const float*)d_in[1];
    const float* Wq  = (const float*)d_in[2];
    const float* bq  = (const float*)d_in[3];
    const float* Wk  = (const float*)d_in[4];
    const float* bk  = (const float*)d_in[5];
    const float* Wv  = (const float*)d_in[6];
    const float* bv  = (const float*)d_in[7];
    const float* Er  = (const float*)d_in[8];
    const float* Wo  = (const float*)d_in[9];
    const float* bo  = (const float*)d_in[10];
    float* out = (float*)d_out;

    short* attnb = (short*)d_ws;                       // M1*512
    short* Y    = attnb + (size_t)M1 * NI;             // 384*1536 (token QKV table)
    short* embb = Y + (size_t)384 * NQ;                // DM*KP
    short* wt   = embb + (size_t)DM * KP;              // NQ*KP
    short* wot  = wt + (size_t)NQ * KP;                // 384*NI
    short* eb   = wot + (size_t)384 * NI;              // SS*DH
    float* QEt  = (float*)(eb + (size_t)SS * DH);      // 8*333*333 f32 (3.55 MB)

    conv_all_kernel<<<(CNT + 255) / 256, 256, 0, stream>>>(Er, emb, Wq, Wk, Wv, Wo,
                                                           eb, embb, wt, wot);
    dim3 g1(3, 12);
    yqkv_kernel<<<g1, 256, 0, stream>>>(embb, wt, bq, bk, bv, Y);
    dim3 g2(3, 3, 8);
    qet_kernel<<<g2, 256, 0, stream>>>(Y, eb, QEt);
    attn_mfma_kernel<<<BB * NH * 3, 512, 0, stream>>>(Y, xs, QEt, attnb);
    dim3 g3((M1 + 127) / 128, 3);
    oproj_mfma_kernel<<<g3, 256, 0, stream>>>(attnb, wot, bo, out);
}

// Round 24
// 104.529 us; speedup vs baseline: 1.0241x; 1.0022x over previous
//
#include <hip/hip_runtime.h>
#include <hip/hip_bf16.h>

#define BB 64
#define SS 333
#define NH 8
#define DH 64
#define NI 512
#define DM 333
#define M1 21312      // BB*SS
#define KP 384        // padded K for vocab GEMM (333 -> 384)
#define NQ 1536       // fused col count [Q|K|V]
#define RS1 1536      // Y row stride (shorts)
#define VT2 110889    // 333*333 (per-head QEt slice)
#define QKSC 0.1803368801111601f   // 0.125 * log2(e)
#define SHFT 23.083120654223414f   // 16 * log2(e)

typedef __attribute__((ext_vector_type(8))) short short8v;
typedef __attribute__((ext_vector_type(4))) float f32x4;

__device__ inline short f2bf(float f) {
    unsigned u = __float_as_uint(f);
    u += 0x7fffu + ((u >> 16) & 1u);
    return (short)(u >> 16);
}

__device__ __forceinline__ void gload16(const void* g, void* l) {
    __builtin_amdgcn_global_load_lds(
        (const __attribute__((address_space(1))) void*)g,
        (__attribute__((address_space(3))) void*)l, 16, 0, 0);
}

// ---------------- K0: all f32->bf16 conversions in ONE launch ----------------
#define CN0 (SS * DH)        // 21312
#define CN1 (DM * KP)        // 127872
#define CN2 (NQ * KP)        // 589824
#define CN3 (384 * NI)       // 196608
#define CNT (CN0 + CN1 + CN2 + CN3)

__global__ __launch_bounds__(256) void conv_all_kernel(
    const float* __restrict__ Er, const float* __restrict__ emb,
    const float* __restrict__ Wq, const float* __restrict__ Wk,
    const float* __restrict__ Wv, const float* __restrict__ Wo,
    short* __restrict__ eb, short* __restrict__ embb,
    short* __restrict__ wt, short* __restrict__ wot)
{
    int i = blockIdx.x * 256 + threadIdx.x;
    if (i < CN0) {
        eb[i] = f2bf(Er[i]);
        return;
    }
    i -= CN0;
    if (i < CN1) {
        int v = i / KP, k = i - v * KP;
        embb[i] = (k < DM) ? f2bf(emb[(size_t)v * DM + k]) : (short)0;
        return;
    }
    i -= CN1;
    if (i < CN2) {
        int n = i / KP, k = i - n * KP;
        int mat = n >> 9, c = n & 511;
        const float* W = (mat == 0) ? Wq : (mat == 1) ? Wk : Wv;
        wt[i] = (k < DM) ? f2bf(W[(size_t)k * NI + c]) : (short)0;
        return;
    }
    i -= CN2;
    if (i < CN3) {
        int n = i >> 9, k = i & 511;
        wot[i] = (n < DM) ? f2bf(Wo[(size_t)k * DM + n]) : (short)0;
    }
}

// ---------------- K1: vocab GEMM  Y[v,n] = embb[v,:] @ wt[n,:] + bias[n] --------------
__global__ __launch_bounds__(256) void yqkv_kernel(
    const short* __restrict__ embb, const short* __restrict__ wt,
    const float* __restrict__ bq, const float* __restrict__ bk, const float* __restrict__ bv,
    short* __restrict__ Y)
{
    __shared__ __align__(16) short abuf[2][128 * 64];
    __shared__ __align__(16) short bbuf[2][128 * 64];

    const int row0 = blockIdx.x * 128;
    const int n0   = blockIdx.y * 128;
    const int t = threadIdx.x;
    const int lane = t & 63, w = t >> 6;
    const int l15 = lane & 15, lq = lane >> 4;
    const int wr = w >> 1, wc = w & 1;

    f32x4 acc[4][4];
#pragma unroll
    for (int mi = 0; mi < 4; ++mi)
#pragma unroll
        for (int nj = 0; nj < 4; ++nj) { f32x4 z = {0.f,0.f,0.f,0.f}; acc[mi][nj] = z; }

    auto stage = [&](int buf, int k0) {
#pragma unroll
        for (int i = 0; i < 4; ++i) {
            int idx = (w * 4 + i) * 64 + lane;
            int row = idx >> 3, sp = idx & 7;
            int ar = row0 + row; ar = ar < DM ? ar : DM - 1;
            gload16(embb + (size_t)ar * KP + k0 + ((sp ^ (row & 7)) << 3),
                    &abuf[buf][(w * 4 + i) * 512]);
        }
#pragma unroll
        for (int i = 0; i < 4; ++i) {
            int idx = (w * 4 + i) * 64 + lane;
            int row = idx >> 3, sp = idx & 7;
            gload16(wt + (size_t)(n0 + row) * KP + k0 + ((sp ^ (row & 7)) << 3),
                    &bbuf[buf][(w * 4 + i) * 512]);
        }
    };

    stage(0, 0);
    __syncthreads();
    for (int tk = 0; tk < 6; ++tk) {
        if (tk < 5) stage((tk + 1) & 1, (tk + 1) * 64);
        const short* ab = abuf[tk & 1];
        const short* bb = bbuf[tk & 1];
#pragma unroll
        for (int kh = 0; kh < 2; ++kh) {
            short8v af[4], bfv[4];
#pragma unroll
            for (int mi = 0; mi < 4; ++mi) {
                int row = wr * 64 + mi * 16 + l15;
                int sp = (lq + 4 * kh) ^ (row & 7);
                af[mi] = *(const short8v*)(ab + row * 64 + sp * 8);
            }
#pragma unroll
            for (int nj = 0; nj < 4; ++nj) {
                int row = wc * 64 + nj * 16 + l15;
                int sp = (lq + 4 * kh) ^ (row & 7);
                bfv[nj] = *(const short8v*)(bb + row * 64 + sp * 8);
            }
            __builtin_amdgcn_s_setprio(1);
#pragma unroll
            for (int mi = 0; mi < 4; ++mi)
#pragma unroll
                for (int nj = 0; nj < 4; ++nj)
                    acc[mi][nj] = __builtin_amdgcn_mfma_f32_16x16x32_bf16(af[mi], bfv[nj], acc[mi][nj], 0, 0, 0);
            __builtin_amdgcn_s_setprio(0);
        }
        __syncthreads();
    }

    const int mat = n0 >> 9;
    const float* bias = (mat == 0) ? bq : (mat == 1) ? bk : bv;
    const int cb = (n0 & 511) + wc * 64;
#pragma unroll
    for (int nj = 0; nj < 4; ++nj) {
        float bvv = bias[cb + nj * 16 + l15];
        int colg = n0 + wc * 64 + nj * 16 + l15;
#pragma unroll
        for (int mi = 0; mi < 4; ++mi)
#pragma unroll
            for (int r = 0; r < 4; ++r) {
                int rowg = row0 + wr * 64 + mi * 16 + lq * 4 + r;
                Y[(size_t)rowg * NQ + colg] = f2bf(acc[mi][nj][r] + bvv);
            }
    }
}

// ---------------- K1b: QE table  QEt[h][v][l] = (0.125*q(v).Er[l] - 16) * log2e -------
// log2e folded so attn uses native exp2 (saves a v_mul per element in the hot loop).
__global__ __launch_bounds__(256) void qet_kernel(
    const short* __restrict__ Y, const short* __restrict__ eb,
    float* __restrict__ QEt)
{
    __shared__ __align__(16) short abuf[128 * 64];
    __shared__ __align__(16) short bbuf[128 * 64];

    const int row0 = blockIdx.x * 128;   // vi tile
    const int n0   = blockIdx.y * 128;   // l tile
    const int h    = blockIdx.z;
    const int t = threadIdx.x;
    const int lane = t & 63, w = t >> 6;
    const int l15 = lane & 15, lq = lane >> 4;
    const int wr = w >> 1, wc = w & 1;

#pragma unroll
    for (int i = 0; i < 4; ++i) {
        int idx = (w * 4 + i) * 64 + lane;
        int row = idx >> 3, sp = idx & 7;
        int ar = row0 + row; ar = ar < DM ? ar : DM - 1;
        gload16(Y + (size_t)ar * RS1 + h * 64 + ((sp ^ (row & 7)) << 3),
                &abuf[(w * 4 + i) * 512]);
    }
#pragma unroll
    for (int i = 0; i < 4; ++i) {
        int idx = (w * 4 + i) * 64 + lane;
        int row = idx >> 3, sp = idx & 7;
        int br = n0 + row; br = br < SS ? br : SS - 1;
        gload16(eb + (size_t)br * DH + ((sp ^ (row & 7)) << 3),
                &bbuf[(w * 4 + i) * 512]);
    }
    __syncthreads();

    f32x4 acc[4][4];
#pragma unroll
    for (int mi = 0; mi < 4; ++mi)
#pragma unroll
        for (int nj = 0; nj < 4; ++nj) { f32x4 z = {0.f,0.f,0.f,0.f}; acc[mi][nj] = z; }

#pragma unroll
    for (int kh = 0; kh < 2; ++kh) {
        short8v af[4], bfv[4];
#pragma unroll
        for (int mi = 0; mi < 4; ++mi) {
            int row = wr * 64 + mi * 16 + l15;
            int sp = (lq + 4 * kh) ^ (row & 7);
            af[mi] = *(const short8v*)(abuf + row * 64 + sp * 8);
        }
#pragma unroll
        for (int nj = 0; nj < 4; ++nj) {
            int row = wc * 64 + nj * 16 + l15;
            int sp = (lq + 4 * kh) ^ (row & 7);
            bfv[nj] = *(const short8v*)(bbuf + row * 64 + sp * 8);
        }
#pragma unroll
        for (int mi = 0; mi < 4; ++mi)
#pragma unroll
            for (int nj = 0; nj < 4; ++nj)
                acc[mi][nj] = __builtin_amdgcn_mfma_f32_16x16x32_bf16(af[mi], bfv[nj], acc[mi][nj], 0, 0, 0);
    }

    float* Qh = QEt + (size_t)h * VT2;
#pragma unroll
    for (int nj = 0; nj < 4; ++nj) {
        int colg = n0 + wc * 64 + nj * 16 + l15;
#pragma unroll
        for (int mi = 0; mi < 4; ++mi)
#pragma unroll
            for (int r = 0; r < 4; ++r) {
                int rowg = row0 + wr * 64 + mi * 16 + lq * 4 + r;
                if (rowg < SS && colg < SS)
                    Qh[(size_t)rowg * SS + colg] = acc[mi][nj][r] * QKSC - SHFT;
            }
    }
}

// ---------------- K2: batch-paired flash MFMA attention, QE-table gather -------------
// Block = (h, ti, batch-pair): group 0 (waves 0-3) = batch 2bp, group 1 = batch 2bp+1,
// BOTH on q-tile ti -> zero idle wave-groups. Dispatch order ti descending.
// P = exp2(qk*QKSC + QEt[tok_i][SS-1-i+j]) (exp + fixed-max folded into the table);
// masked -> 0; clamps RETAINED (R22 lesson: OOB gathers cost more than the saved ops);
// deferred row-sum at epilogue. waves_per_eu(4,4): VGPR 64, no spill. LDS 66.7 KB.
__global__ __launch_bounds__(512) __attribute__((amdgpu_waves_per_eu(4, 4)))
void attn_mfma_kernel(
    const short* __restrict__ Y, const int* __restrict__ xs,
    const float* __restrict__ QEt, short* __restrict__ attnb)
{
    __shared__ __align__(16) short k_lds[2][64 * 64];  // per-group [key][d], seg-swz key&7
    __shared__ __align__(16) short vT_lds[2][64 * 64]; // per-group [d][key], seg-swz d&7
    __shared__ __align__(16) short vrow[2][64 * 64];   // per-group V row-staging (linear)
    __shared__ __align__(16) short p_lds[128 * 64];    // 8 waves x 2KB P tiles
    __shared__ int tok_lds[2][SS];

    const int p = blockIdx.x;
    const int h = p & 7;                 // XCD pin (p%8)
    const int rem = p >> 3;
    const int tid = rem >> 5;            // 0..5, dispatch-ordered
    const int bp  = rem & 31;            // batch pair
    const int ti  = 5 - tid;             // long blocks first
    const int t = threadIdx.x;           // 0..511
    const int lane = t & 63, w = t >> 6; // w 0..7
    const int l15 = lane & 15, lq = lane >> 4;
    const int g  = w >> 2;               // group (batch select)
    const int wl = w & 3;                // wave-in-group = strip index
    const int b  = bp * 2 + g;
    const int iw = ti * 64 + 16 * wl;
    const int tl = t & 255;              // thread within group

    // stage both batches' token ids
    for (int idx = t; idx < SS; idx += 512) tok_lds[0][idx] = xs[(bp * 2) * SS + idx];
    for (int idx = t; idx < SS; idx += 512) tok_lds[1][idx] = xs[(bp * 2 + 1) * SS + idx];
    __syncthreads();

    const short* Yh = Y + h * 64;
    const float* QEh = QEt + (size_t)h * VT2;
    const int* tok = tok_lds[g];

    // ---- Q fragments + per-row QEt row offsets ----
    int qr = iw + l15; if (qr > SS - 1) qr = SS - 1;
    const short* qrow = Yh + (size_t)tok[qr] * RS1;
    const short8v qa0 = *(const short8v*)(qrow + lq * 8);
    const short8v qa1 = *(const short8v*)(qrow + 32 + lq * 8);

    int irow[4];
#pragma unroll
    for (int r = 0; r < 4; ++r) {
        int i_ = iw + lq * 4 + r; if (i_ > SS - 1) i_ = SS - 1;
        irow[r] = tok[i_] * SS;
    }

    float l4[4];
    f32x4 o[4];
#pragma unroll
    for (int r = 0; r < 4; ++r) { l4[r] = 0.f; }
#pragma unroll
    for (int nd = 0; nd < 4; ++nd) { f32x4 z = {0.f, 0.f, 0.f, 0.f}; o[nd] = z; }

    asm volatile("s_waitcnt vmcnt(0)" ::: "memory");

    for (int js = 0; js <= ti; ++js) {
        const int j0 = js * 64;
        __syncthreads();                 // barrier A: prev compute done, buffers free
        // ---- V row stage (group-local: 2 gloads/thread; oldest on the counter) ----
#pragma unroll
        for (int it = 0; it < 2; ++it) {
            int task = it * 256 + tl;
            int row = task >> 3, sp = task & 7;
            int jg = j0 + row; if (jg > SS - 1) jg = SS - 1;
            gload16(Yh + (size_t)tok[jg] * RS1 + 1024 + ((sp ^ (row & 7)) << 3),
                    &vrow[g][(size_t)(it * 256 + (tl & 192)) * 8]);
        }
        // ---- K stage (group-local: 2 gloads/thread) ----
#pragma unroll
        for (int it = 0; it < 2; ++it) {
            int task = it * 256 + tl;
            int row = task >> 3, sp = task & 7;
            int jg = j0 + row; if (jg > SS - 1) jg = SS - 1;
            gload16(Yh + (size_t)tok[jg] * RS1 + 512 + ((sp ^ (row & 7)) << 3),
                    &k_lds[g][(size_t)(it * 256 + (tl & 192)) * 8]);
        }
        // wait the 2 oldest (V) gloads; K drains at the barrier
        asm volatile("s_waitcnt vmcnt(2)" ::: "memory");
        // ---- wave-local V transpose: wave wl transposes its own octets {wl, 4+wl} ----
#pragma unroll
        for (int it = 0; it < 2; ++it) {
            const int kc = it * 4 + wl;
            const int d = lane;
            short8v vv;
#pragma unroll
            for (int j = 0; j < 8; ++j)
                vv[j] = vrow[g][(kc * 8 + j) * 64 + (((d >> 3) ^ j) << 3) + (d & 7)];
            *(short8v*)(vT_lds[g] + (size_t)d * 64 + ((kc ^ (d & 7)) << 3)) = vv;
        }
        __syncthreads();                 // barrier B: k_lds + vT ready

        // ---- every wave active: QK, QEt gather, P write, PV ----
        {
            const short* kb = k_lds[g];
            f32x4 sc[4];
            __builtin_amdgcn_s_setprio(1);
#pragma unroll
            for (int n = 0; n < 4; ++n) {
                int row = n * 16 + l15;
                short8v k0 = *(const short8v*)((char*)kb + ((row * 128 + lq * 16) ^ ((row & 7) << 4)));
                short8v k1 = *(const short8v*)((char*)kb + ((row * 128 + 64 + lq * 16) ^ ((row & 7) << 4)));
                f32x4 z = {0.f, 0.f, 0.f, 0.f};
                z = __builtin_amdgcn_mfma_f32_16x16x32_bf16(qa0, k0, z, 0, 0, 0);
                sc[n] = __builtin_amdgcn_mfma_f32_16x16x32_bf16(qa1, k1, z, 0, 0, 0);
            }
            __builtin_amdgcn_s_setprio(0);

            short* pw = p_lds + w * 1024;
#pragma unroll
            for (int n = 0; n < 4; ++n) {
                float psum[4];
#pragma unroll
                for (int r = 0; r < 4; ++r) {
                    int irel = lq * 4 + r;
                    int li = (SS - 1) - (iw + irel) + j0 + n * 16 + l15;
                    li = li < 0 ? 0 : (li > SS - 1 ? SS - 1 : li);
                    float qet = QEh[irow[r] + li];
                    int jrel = n * 16 + l15;
                    bool ok = (j0 + jrel) <= (iw + irel);
                    float pv = ok ? __builtin_amdgcn_exp2f(sc[n][r] * QKSC + qet) : 0.f;
                    psum[r] = pv;
                    *(short*)((char*)pw + ((irel * 128 + jrel * 2) ^ ((irel & 7) << 4))) = f2bf(pv);
                }
#pragma unroll
                for (int r = 0; r < 4; ++r)
                    l4[r] += psum[r];
            }

            __builtin_amdgcn_s_setprio(1);
#pragma unroll
            for (int kb2 = 0; kb2 < 2; ++kb2) {
                short8v pa = *(const short8v*)((char*)pw + ((l15 * 128 + kb2 * 64 + lq * 16) ^ ((l15 & 7) << 4)));
#pragma unroll
                for (int nd = 0; nd < 4; ++nd) {
                    int d = nd * 16 + l15;
                    short8v vf = *(const short8v*)((char*)vT_lds[g] + ((size_t)d * 128 + (((kb2 * 4 + lq) ^ (d & 7)) << 4)));
                    o[nd] = __builtin_amdgcn_mfma_f32_16x16x32_bf16(pa, vf, o[nd], 0, 0, 0);
                }
            }
            __builtin_amdgcn_s_setprio(0);
        }
    }

    // ---- epilogue: finish l-reduction, normalize, store bf16 (B,S,INNER) ----
#pragma unroll
    for (int r = 0; r < 4; ++r) {
        float ls = l4[r];
        ls += __shfl_xor(ls, 1);
        ls += __shfl_xor(ls, 2);
        ls += __shfl_xor(ls, 4);
        ls += __shfl_xor(ls, 8);
        int i = iw + lq * 4 + r;
        if (i < SS) {
            float rl = 1.0f / ls;
#pragma unroll
            for (int nd = 0; nd < 4; ++nd)
                attnb[(size_t)(b * SS + i) * NI + h * 64 + nd * 16 + l15] = f2bf(o[nd][r] * rl);
        }
    }
}

// ---------------- K3: out = attnb[M1,512] @ wot^T + bo, f32 out ----------------
__global__ __launch_bounds__(256) void oproj_mfma_kernel(
    const short* __restrict__ ab_g, const short* __restrict__ wot,
    const float* __restrict__ bo, float* __restrict__ out)
{
    __shared__ __align__(16) short abuf[2][128 * 64];
    __shared__ __align__(16) short bbuf[2][128 * 64];

    const int row0 = blockIdx.x * 128;
    const int n0   = blockIdx.y * 128;
    const int t = threadIdx.x;
    const int lane = t & 63, w = t >> 6;
    const int l15 = lane & 15, lq = lane >> 4;
    const int wr = w >> 1, wc = w & 1;

    f32x4 acc[4][4];
#pragma unroll
    for (int mi = 0; mi < 4; ++mi)
#pragma unroll
        for (int nj = 0; nj < 4; ++nj) { f32x4 z = {0.f,0.f,0.f,0.f}; acc[mi][nj] = z; }

    auto stage = [&](int buf, int k0) {
#pragma unroll
        for (int i = 0; i < 4; ++i) {
            int idx = (w * 4 + i) * 64 + lane;
            int row = idx >> 3, sp = idx & 7;
            int rg = row0 + row; rg = rg < M1 ? rg : M1 - 1;
            gload16(ab_g + (size_t)rg * NI + k0 + ((sp ^ (row & 7)) << 3),
                    &abuf[buf][(w * 4 + i) * 512]);
        }
#pragma unroll
        for (int i = 0; i < 4; ++i) {
            int idx = (w * 4 + i) * 64 + lane;
            int row = idx >> 3, sp = idx & 7;
            gload16(wot + (size_t)(n0 + row) * NI + k0 + ((sp ^ (row & 7)) << 3),
                    &bbuf[buf][(w * 4 + i) * 512]);
        }
    };

    stage(0, 0);
    __syncthreads();
    for (int tk = 0; tk < 8; ++tk) {
        if (tk < 7) stage((tk + 1) & 1, (tk + 1) * 64);
        const short* ab = abuf[tk & 1];
        const short* bb = bbuf[tk & 1];
#pragma unroll
        for (int kh = 0; kh < 2; ++kh) {
            short8v af[4], bfv[4];
#pragma unroll
            for (int mi = 0; mi < 4; ++mi) {
                int row = wr * 64 + mi * 16 + l15;
                int sp = (lq + 4 * kh) ^ (row & 7);
                af[mi] = *(const short8v*)(ab + row * 64 + sp * 8);
            }
#pragma unroll
            for (int nj = 0; nj < 4; ++nj) {
                int row = wc * 64 + nj * 16 + l15;
                int sp = (lq + 4 * kh) ^ (row & 7);
                bfv[nj] = *(const short8v*)(bb + row * 64 + sp * 8);
            }
            __builtin_amdgcn_s_setprio(1);
#pragma unroll
            for (int mi = 0; mi < 4; ++mi)
#pragma unroll
                for (int nj = 0; nj < 4; ++nj)
                    acc[mi][nj] = __builtin_amdgcn_mfma_f32_16x16x32_bf16(af[mi], bfv[nj], acc[mi][nj], 0, 0, 0);
            __builtin_amdgcn_s_setprio(0);
        }
        __syncthreads();
    }

#pragma unroll
    for (int nj = 0; nj < 4; ++nj) {
        int colg = n0 + wc * 64 + nj * 16 + l15;
        float bvv = (colg < DM) ? bo[colg] : 0.f;
#pragma unroll
        for (int mi = 0; mi < 4; ++mi)
#pragma unroll
            for (int r = 0; r < 4; ++r) {
                int rowg = row0 + wr * 64 + mi * 16 + lq * 4 + r;
                if (rowg < M1 && colg < DM)
                    out[(size_t)rowg * DM + colg] = acc[mi][nj][r] + bvv;
            }
    }
}

extern "C" void kernel_launch(void* const* d_in, const int* in_sizes, int n_in,
                              void* d_out, int out_size, void* d_ws, size_t ws_size,
                              hipStream_t stream) {
    const int*   xs  = (const int*)d_in[0];
    const float* emb = (const float*)d_in[1];
    const float* Wq  = (const float*)d_in[2];
    const float* bq  = (const float*)d_in[3];
    const float* Wk  = (const float*)d_in[4];
    const float* bk  = (const float*)d_in[5];
    const float* Wv  = (const float*)d_in[6];
    const float* bv  = (const float*)d_in[7];
    const float* Er  = (const float*)d_in[8];
    const float* Wo  = (const float*)d_in[9];
    const float* bo  = (const float*)d_in[10];
    float* out = (float*)d_out;

    short* attnb = (short*)d_ws;                       // M1*512
    short* Y    = attnb + (size_t)M1 * NI;             // 384*1536 (token QKV table)
    short* embb = Y + (size_t)384 * NQ;                // DM*KP
    short* wt   = embb + (size_t)DM * KP;              // NQ*KP
    short* wot  = wt + (size_t)NQ * KP;                // 384*NI
    short* eb   = wot + (size_t)384 * NI;              // SS*DH
    float* QEt  = (float*)(eb + (size_t)SS * DH);      // 8*333*333 f32 (3.55 MB)

    conv_all_kernel<<<(CNT + 255) / 256, 256, 0, stream>>>(Er, emb, Wq, Wk, Wv, Wo,
                                                           eb, embb, wt, wot);
    dim3 g1(3, 12);
    yqkv_kernel<<<g1, 256, 0, stream>>>(embb, wt, bq, bk, bv, Y);
    dim3 g2(3, 3, 8);
    qet_kernel<<<g2, 256, 0, stream>>>(Y, eb, QEt);
    attn_mfma_kernel<<<BB * NH * 3, 512, 0, stream>>>(Y, xs, QEt, attnb);
    dim3 g3((M1 + 127) / 128, 3);
    oproj_mfma_kernel<<<g3, 256, 0, stream>>>(attnb, wot, bo, out);
}